// Round 6
// baseline (371.622 us; speedup 1.0000x reference)
//
#include <hip/hip_runtime.h>
#include <hip/hip_bf16.h>

typedef unsigned short u16;
typedef unsigned int u32;
typedef float f32x4 __attribute__((ext_vector_type(4)));
typedef short s16x8 __attribute__((ext_vector_type(8)));

#define MFMA16(a, b, c) __builtin_amdgcn_mfma_f32_16x16x32_bf16(a, b, c, 0, 0, 0)

#define NN 4096
#define CC 256
#define CQ 64
#define NBLK 512

__device__ __forceinline__ u16 f2bf(float x) {          // round-nearest-even
    union { float f; u32 u; } v; v.f = x;
    return (u16)((v.u + 0x7FFFu + ((v.u >> 16) & 1u)) >> 16);
}
__device__ __forceinline__ u16 f2bf_t(float x) {        // truncate (hot path)
    union { float f; u32 u; } v; v.f = x;
    return (u16)(v.u >> 16);
}
__device__ __forceinline__ float bf2f(u16 u) {
    union { u32 u; float f; } v; v.u = ((u32)u) << 16;
    return v.f;
}
// async global->LDS, 16B/lane; dst = wave-uniform base + lane*16 (m104)
__device__ __forceinline__ void gll16(const void* g, void* l) {
    __builtin_amdgcn_global_load_lds(
        (const __attribute__((address_space(1))) void*)g,
        (__attribute__((address_space(3))) void*)l, 16, 0, 0);
}

// Device-scope grid barrier. SAFE: all 512 blocks are co-resident by capacity
// (LDS 53.2KB -> 3 blocks/CU cap = 768 >= 512; VGPR<=128 via launch_bounds).
// Release/acquire at AGENT scope handles cross-XCD L2 wb/inv (G16) — required
// because ws regions are written in one phase and read on other XCDs later.
__device__ __forceinline__ void gbar(int* cnt) {
    __syncthreads();
    if (threadIdx.x == 0) {
        __hip_atomic_fetch_add(cnt, 1, __ATOMIC_RELEASE, __HIP_MEMORY_SCOPE_AGENT);
        while (__hip_atomic_load(cnt, __ATOMIC_ACQUIRE, __HIP_MEMORY_SCOPE_AGENT) < NBLK)
            __builtin_amdgcn_s_sleep(2);
    }
    __syncthreads();
}

// ---------------------------------------------------------------------------
// Phase 0: x[b][c][n] f32 -> xT[b][n][c] bf16 (1024 tile units, 2/block);
//          blocks 0..47: Wq|Wk|Wv -> wbf[384][256] bf16 (2048 f32 each)
// ---------------------------------------------------------------------------
__device__ void phase_prep(const float* __restrict__ x, const float* __restrict__ Wq,
                           const float* __restrict__ Wk, const float* __restrict__ Wv,
                           u16* __restrict__ xT, u16* __restrict__ wbf, u16* SMEM)
{
    const int t = threadIdx.x;
    float* tile = (float*)SMEM;              // [64][65] f32 = 16640 B
    for (int u = blockIdx.x; u < 1024; u += NBLK) {   // exactly 2 iters/block
        const int b = u >> 8, ctile = (u >> 6) & 3, ntile = u & 63;
        const int c0 = ctile * 64, n0 = ntile * 64;
        for (int it = 0; it < 2; it++) {
            const int idx = it * 512 + t;
            const int ci = idx >> 4, nj = (idx & 15) * 4;
            const float4 v4 = *(const float4*)(x + ((size_t)(b * CC + c0 + ci)) * NN + n0 + nj);
            tile[(nj + 0) * 65 + ci] = v4.x;
            tile[(nj + 1) * 65 + ci] = v4.y;
            tile[(nj + 2) * 65 + ci] = v4.z;
            tile[(nj + 3) * 65 + ci] = v4.w;
        }
        __syncthreads();
        const int r = t >> 3, c8 = (t & 7) * 8;
        union { u16 h[8]; uint4 q; } pk;
        for (int j = 0; j < 8; j++) pk.h[j] = f2bf(tile[r * 65 + c8 + j]);
        *(uint4*)(xT + ((size_t)(b * NN + n0 + r)) * CC + c0 + c8) = pk.q;
        __syncthreads();
    }
    if (blockIdx.x < 48) {
        const int flat = blockIdx.x * 2048 + t * 4;
        const int o = flat >> 8, c = flat & 255;
        const float* src = (o < 64)  ? (Wq + (size_t)o * CC + c)
                         : (o < 128) ? (Wk + (size_t)(o - 64) * CC + c)
                                     : (Wv + (size_t)(o - 128) * CC + c);
        const float4 v4 = *(const float4*)src;
        union { u16 h[4]; uint2 d; } pk;
        pk.h[0] = f2bf(v4.x); pk.h[1] = f2bf(v4.y);
        pk.h[2] = f2bf(v4.z); pk.h[3] = f2bf(v4.w);
        *(uint2*)(wbf + (size_t)o * CC + c) = pk.d;
    }
}

// ---------------------------------------------------------------------------
// Phase 1: fused QKV projection GEMM (R5 structure; 512 blocks = 4b x 128 nt)
// ---------------------------------------------------------------------------
__device__ void phase_qkv(const u16* __restrict__ xT, const u16* __restrict__ wbf,
                          const float* __restrict__ bq, const float* __restrict__ bk,
                          const float* __restrict__ bv,
                          u16* __restrict__ qT, u16* __restrict__ kT,
                          u16* __restrict__ v, u16* SMEM)
{
    u16* Ws = SMEM;             // [384][64] swizzled
    u16* Xs = SMEM + 384 * 64;  // [32][64] swizzled

    const int bid = blockIdx.x;
    const int b = bid >> 7, n0 = (bid & 127) * 32;
    const int t = threadIdx.x, lane = t & 63, w = t >> 6;
    const int col = lane & 15, quad = lane >> 4;

    f32x4 acc[3][2];
    for (int i = 0; i < 3; i++) { acc[i][0] = f32x4{0,0,0,0}; acc[i][1] = f32x4{0,0,0,0}; }

    for (int cc = 0; cc < 4; cc++) {
        const int c0 = cc * 64;
        for (int m = 0; m < 6; m++) {
            const int g = m * 512 + t;
            const int row = g >> 3, ch = g & 7;
            gll16(wbf + (size_t)row * CC + c0 + ((ch ^ (row & 7)) * 8), Ws + g * 8);
        }
        if (w < 4) {
            const int g = w * 64 + lane;
            const int n = g >> 3, ch = g & 7;
            gll16(xT + ((size_t)(b * NN + n0 + n)) * CC + c0 + ((ch ^ (n & 7)) * 8),
                  Xs + g * 8);
        }
        __syncthreads();
        for (int kk = 0; kk < 2; kk++) {
            s16x8 bx[2];
            for (int nt2 = 0; nt2 < 2; nt2++) {
                const int n = nt2 * 16 + col;
                bx[nt2] = *(const s16x8*)&Xs[n * 64 + (((kk * 4 + quad) ^ (n & 7)) * 8)];
            }
            for (int ot = 0; ot < 3; ot++) {
                const int row = w * 48 + ot * 16 + col;
                const s16x8 a = *(const s16x8*)&Ws[row * 64 + (((kk * 4 + quad) ^ (row & 7)) * 8)];
                acc[ot][0] = MFMA16(a, bx[0], acc[ot][0]);
                acc[ot][1] = MFMA16(a, bx[1], acc[ot][1]);
            }
        }
        __syncthreads();
    }
    for (int ot = 0; ot < 3; ot++) {
        const int og = w * 48 + ot * 16 + quad * 4;   // wave-uniform region
        for (int nt2 = 0; nt2 < 2; nt2++) {
            const int n = n0 + nt2 * 16 + col;
            if (og < 64) {
                union { u16 h[4]; uint2 d; } pk;
                for (int r = 0; r < 4; r++) pk.h[r] = f2bf(acc[ot][nt2][r] + bq[og + r]);
                *(uint2*)(qT + ((size_t)(b * NN + n)) * CQ + og) = pk.d;
            } else if (og < 128) {
                union { u16 h[4]; uint2 d; } pk;
                for (int r = 0; r < 4; r++) pk.h[r] = f2bf(acc[ot][nt2][r] + bk[og - 64 + r]);
                *(uint2*)(kT + ((size_t)(b * NN + n)) * CQ + (og - 64)) = pk.d;
            } else {
                for (int r = 0; r < 4; r++)
                    v[((size_t)(b * CC + og - 128 + r)) * NN + n] =
                        f2bf(acc[ot][nt2][r] + bv[og - 128 + r]);
            }
        }
    }
}

// ---------------------------------------------------------------------------
// Phase 2: flash attention, j-split x2 (R5 structure + V bank swizzle + trunc
// cvt for P). LDS u16 offsets: K0@0 K1@2048 | V0@4096 V1@12288 | P@20480 (x2,
// stride 40). V content swizzle: chunk ch of row r stored at ch^((r>>1)&3) ->
// PV b128 read start-banks 2-way instead of 8-way (R5's 6.4e6 conflicts).
// ---------------------------------------------------------------------------
__device__ void phase_flash(const u16* __restrict__ qT, const u16* __restrict__ kT,
                            const u16* __restrict__ v,
                            u16* __restrict__ Op0, float* __restrict__ Op1,
                            float* __restrict__ lws, u16* SMEM)
{
    u16* sm = SMEM;
    float* ls = (float*)(SMEM + 25600);    // [2][64] f32

    const int bid = blockIdx.x;
    const int p = bid & 7;                 // XCD pin
    const int b = p >> 1, jh = p & 1;
    const int n0 = (bid >> 3) * 64;
    const int jb = jh * 2048;
    const int t = threadIdx.x;
    const int lane = t & 63, wv = t >> 6;
    const int col = lane & 15, quad = lane >> 4;
    const int strip = wv & 3, jhi = wv >> 2;   // S-phase identity
    const int ih = wv >> 2, cq = wv & 3;       // PV-phase identity
    const int key2 = (col >> 1) & 3;           // V de-swizzle key

    s16x8 aq[2];
    {
        const u16* qp = qT + ((size_t)(b * NN + n0 + strip * 16 + col)) * CQ + quad * 8;
        aq[0] = *(const s16x8*)qp;
        aq[1] = *(const s16x8*)(qp + 32);
    }

    f32x4 o_[2][4];
    for (int i = 0; i < 2; i++) for (int j = 0; j < 4; j++) o_[i][j] = f32x4{0,0,0,0};
    float lac[4] = {0.f, 0.f, 0.f, 0.f};

    const int kg = wv * 64 + lane;             // valid for wv<4
    const int krow = kg >> 3;
    const u16* ksrc = kT + ((size_t)(b * NN + jb + krow)) * CQ + (((kg & 7) ^ (krow & 7)) * 8);
    const int kdo = kg * 8;
    const u16* vsrc[2];
    int vdo[2];
    for (int m = 0; m < 2; m++) {
        const int g = m * 512 + t;
        const int row = g >> 2;
        const int chc = (g & 3) ^ ((row >> 1) & 3);   // content chunk for this slot
        vdo[m] = g * 8;
        vsrc[m] = v + ((size_t)(b * CC + row)) * NN + jb + chc * 8;
    }

    auto issueK = [&](int jt, int kb) {
        if (wv < 4) gll16(ksrc + (size_t)jt * 32 * CQ, sm + kb * 2048 + kdo);
    };
    auto issueV = [&](int jt, int vb) {
        u16* base = sm + 4096 + vb * 8192;
        for (int m = 0; m < 2; m++)
            gll16(vsrc[m] + jt * 32, base + vdo[m]);
    };
    auto S_phase = [&](int kb, int pb) {
        const u16* Kb = sm + kb * 2048;
        u16* Pb = sm + 20480 + pb * 2560;
        f32x4 s = f32x4{0,0,0,0};
        for (int kk = 0; kk < 2; kk++) {
            const int jrow = jhi * 16 + col;
            const s16x8 bk_ = *(const s16x8*)
                &Kb[jrow * 64 + (((kk * 4 + quad) ^ (jrow & 7)) * 8)];
            s = MFMA16(aq[kk], bk_, s);
        }
        for (int r = 0; r < 4; r++) {
            const float pv = __expf(fminf(s[r], 60.f));
            lac[r] += pv;
            Pb[(strip * 16 + quad * 4 + r) * 40 + jhi * 16 + col] = f2bf_t(pv);
        }
    };
    auto PV_phase = [&](int pb, int vb) {
        const u16* Pb = sm + 20480 + pb * 2560;
        const u16* Vb = sm + 4096 + vb * 8192;
        s16x8 pa[2];
        for (int it2 = 0; it2 < 2; it2++)
            pa[it2] = *(const s16x8*)&Pb[((ih * 2 + it2) * 16 + col) * 40 + quad * 8];
        for (int ct = 0; ct < 4; ct++) {
            const int c = cq * 64 + ct * 16 + col;
            const s16x8 bv_ = *(const s16x8*)&Vb[c * 32 + ((quad ^ key2) * 8)];
            o_[0][ct] = MFMA16(pa[0], bv_, o_[0][ct]);
            o_[1][ct] = MFMA16(pa[1], bv_, o_[1][ct]);
        }
    };

    issueK(0, 0);
    issueV(0, 0);
    issueK(1, 1);
    __syncthreads();
    S_phase(0, 0);

    int vcur = 0, pcur = 0;
    for (int m = 0; m < 64; m++) {
        __syncthreads();      // drains prior-iter DMAs; P[pcur] visible
        issueV((m + 1 < 64) ? m + 1 : 63, vcur ^ 1);
        issueK((m + 2 < 64) ? m + 2 : 63, m & 1);
        PV_phase(pcur, vcur);
        if (m < 63) S_phase((m + 1) & 1, pcur ^ 1);
        vcur ^= 1; pcur ^= 1;
    }

    for (int r = 0; r < 4; r++) {
        float lv = lac[r];
        lv += __shfl_xor(lv, 1, 64);
        lv += __shfl_xor(lv, 2, 64);
        lv += __shfl_xor(lv, 4, 64);
        lv += __shfl_xor(lv, 8, 64);
        lac[r] = lv;
    }
    if (col == 0)
        for (int r = 0; r < 4; r++)
            ls[jhi * 64 + strip * 16 + quad * 4 + r] = lac[r];
    __syncthreads();   // drains trailing DMAs before sm reuse; ls visible
    if (t < 64)
        lws[(size_t)jh * 4 * NN + (size_t)b * NN + n0 + t] = ls[t] + ls[64 + t];

    // epilogue: transpose O through LDS in 2 rounds of 128 c
    float* Tf = (float*)sm;    // [128][68] f32
    u16*  Tu = sm;             // [128][136] u16
    for (int rd = 0; rd < 2; rd++) {
        if ((cq >> 1) == rd) {
            const int cl = (cq & 1) * 64;
            for (int it2 = 0; it2 < 2; it2++) {
                const int ib = (ih * 2 + it2) * 16 + quad * 4;
                for (int ct = 0; ct < 4; ct++) {
                    const int c = cl + ct * 16 + col;
                    if (jh == 0) {
                        union { u16 h[4]; uint2 d; } pk;
                        for (int r = 0; r < 4; r++) pk.h[r] = f2bf(o_[it2][ct][r]);
                        *(uint2*)&Tu[c * 136 + ib] = pk.d;
                    } else {
                        *(float2*)&Tf[c * 68 + ib] = float2{o_[it2][ct][0], o_[it2][ct][1]};
                        *(float2*)&Tf[c * 68 + ib + 2] = float2{o_[it2][ct][2], o_[it2][ct][3]};
                    }
                }
            }
        }
        __syncthreads();
        const int cl = t >> 2, i0 = (t & 3) * 16;
        const int c = rd * 128 + cl;
        if (jh == 0) {
            u16* dst = Op0 + ((size_t)(b * CC + c)) * NN + n0 + i0;
            *(uint4*)dst       = *(const uint4*)&Tu[cl * 136 + i0];
            *(uint4*)(dst + 8) = *(const uint4*)&Tu[cl * 136 + i0 + 8];
        } else {
            float* dst = Op1 + ((size_t)(b * CC + c)) * NN + n0 + i0;
            for (int k = 0; k < 4; k++)
                *(float4*)(dst + k * 4) = *(const float4*)&Tf[cl * 68 + i0 + k * 4];
        }
        __syncthreads();
    }
}

// ---------------------------------------------------------------------------
// Phase 3: out = x + gamma * (O0 + O1) / (l0 + l1)   (in-place over d_out=O1)
// ---------------------------------------------------------------------------
__device__ void phase_combine(const float* __restrict__ x, const u16* __restrict__ Op0,
                              const float* __restrict__ lws, const float* __restrict__ gamma,
                              float* __restrict__ out)
{
    const float g = gamma[0];
    for (int pass = 0; pass < 4; pass++) {
        const size_t idx = ((size_t)pass * 262144 + (size_t)blockIdx.x * 512 + threadIdx.x) * 4;
        const int b = (int)(idx >> 20);
        const int n = (int)(idx & (NN - 1));
        const float4 xv = *(const float4*)(x + idx);
        const float4 o1 = *(const float4*)(out + idx);
        const uint2 o0 = *(const uint2*)(Op0 + idx);
        const float4 l0 = *(const float4*)(lws + (size_t)b * NN + n);
        const float4 l1 = *(const float4*)(lws + (size_t)4 * NN + (size_t)b * NN + n);
        float4 r;
        r.x = xv.x + g * (bf2f((u16)(o0.x & 0xffff))  + o1.x) / (l0.x + l1.x);
        r.y = xv.y + g * (bf2f((u16)(o0.x >> 16))     + o1.y) / (l0.y + l1.y);
        r.z = xv.z + g * (bf2f((u16)(o0.y & 0xffff))  + o1.z) / (l0.z + l1.z);
        r.w = xv.w + g * (bf2f((u16)(o0.y >> 16))     + o1.w) / (l0.w + l1.w);
        *(float4*)(out + idx) = r;
    }
}

// ---------------------------------------------------------------------------
// Persistent mega-kernel: prep | qkv | flash | combine with grid barriers.
// ---------------------------------------------------------------------------
__global__ __launch_bounds__(512, 4) void pam_mega(
    const float* __restrict__ x, const float* __restrict__ Wq,
    const float* __restrict__ bq, const float* __restrict__ Wk,
    const float* __restrict__ bk, const float* __restrict__ Wv,
    const float* __restrict__ bv, const float* __restrict__ gamma,
    u16* xT, u16* wbf, u16* qT, u16* kT, u16* v,
    float* lws, int* ctr, float* out)
{
    __shared__ __align__(16) u16 SMEM[26624];   // 53248 B (union of all phases)

    phase_prep(x, Wq, Wk, Wv, xT, wbf, SMEM);
    gbar(ctr + 0);
    phase_qkv(xT, wbf, bq, bk, bv, qT, kT, v, SMEM);
    gbar(ctr + 1);
    phase_flash(qT, kT, v, /*Op0=*/xT, /*Op1=*/out, lws, SMEM);
    gbar(ctr + 2);
    phase_combine(x, /*Op0=*/xT, lws, gamma, out);
}

// ---------------------------------------------------------------------------
extern "C" void kernel_launch(void* const* d_in, const int* in_sizes, int n_in,
                              void* d_out, int out_size, void* d_ws, size_t ws_size,
                              hipStream_t stream)
{
    const float* x     = (const float*)d_in[0];
    const float* Wq    = (const float*)d_in[1];
    const float* bq    = (const float*)d_in[2];
    const float* Wk    = (const float*)d_in[3];
    const float* bk    = (const float*)d_in[4];
    const float* Wv    = (const float*)d_in[5];
    const float* bv    = (const float*)d_in[6];
    const float* gamma = (const float*)d_in[7];
    float* out = (float*)d_out;

    // ws (u16): xT 8.39MB (reused as Op0) | wbf 196KB (lws) | qT 2.1MB |
    //           kT 2.1MB | v 8.39MB | ctr 12B   (~21.2 MB total)
    u16* xT  = (u16*)d_ws;
    u16* wbf = xT  + (size_t)4 * NN * CC;
    u16* qT  = wbf + (size_t)384 * CC;
    u16* kT  = qT  + (size_t)4 * NN * CQ;
    u16* vw  = kT  + (size_t)4 * NN * CQ;
    int* ctr = (int*)(vw + (size_t)4 * CC * NN);
    float* lws = (float*)wbf;      // wbf dead after qkv phase

    hipMemsetAsync(ctr, 0, 3 * sizeof(int), stream);
    pam_mega<<<NBLK, 512, 0, stream>>>(x, Wq, bq, Wk, bk, Wv, bv, gamma,
                                       xT, wbf, qT, kT, vw, lws, ctr, out);
}

// Round 7
// 183.735 us; speedup vs baseline: 2.0226x; 2.0226x over previous
//
#include <hip/hip_runtime.h>
#include <hip/hip_bf16.h>

typedef unsigned short u16;
typedef unsigned int u32;
typedef float f32x4 __attribute__((ext_vector_type(4)));
typedef short s16x8 __attribute__((ext_vector_type(8)));

#define MFMA16(a, b, c) __builtin_amdgcn_mfma_f32_16x16x32_bf16(a, b, c, 0, 0, 0)

#define NN 4096
#define CC 256
#define CQ 64

__device__ __forceinline__ u16 f2bf(float x) {          // round-nearest-even
    union { float f; u32 u; } v; v.f = x;
    return (u16)((v.u + 0x7FFFu + ((v.u >> 16) & 1u)) >> 16);
}
__device__ __forceinline__ u16 f2bf_t(float x) {        // truncate (hot path; P only)
    union { float f; u32 u; } v; v.f = x;
    return (u16)(v.u >> 16);
}
__device__ __forceinline__ float bf2f(u16 u) {
    union { u32 u; float f; } v; v.u = ((u32)u) << 16;
    return v.f;
}
// async global->LDS, 16B/lane; dst = wave-uniform base + lane*16 (m104)
__device__ __forceinline__ void gll16(const void* g, void* l) {
    __builtin_amdgcn_global_load_lds(
        (const __attribute__((address_space(1))) void*)g,
        (__attribute__((address_space(3))) void*)l, 16, 0, 0);
}

// ---------------------------------------------------------------------------
// prep: blocks 0..1023: x[b][c][n] f32 -> xT[b][n][c] bf16 (LDS transpose)
//       blocks 1024..1119: Wq|Wk|Wv f32 -> wbf[384][256] bf16
// ---------------------------------------------------------------------------
__global__ __launch_bounds__(256) void prep(
    const float* __restrict__ x, const float* __restrict__ Wq,
    const float* __restrict__ Wk, const float* __restrict__ Wv,
    u16* __restrict__ xT, u16* __restrict__ wbf)
{
    const int bid = blockIdx.x, t = threadIdx.x;
    if (bid < 1024) {
        __shared__ float tile[64 * 65];
        const int b = bid >> 8, ctile = (bid >> 6) & 3, ntile = bid & 63;
        const int c0 = ctile * 64, n0 = ntile * 64;
        const int cw = t >> 4, nj = (t & 15) * 4;
        for (int it = 0; it < 4; it++) {
            const int ci = it * 16 + cw;
            const float4 v4 = *(const float4*)(x + ((size_t)(b * CC + c0 + ci)) * NN + n0 + nj);
            tile[(nj + 0) * 65 + ci] = v4.x;
            tile[(nj + 1) * 65 + ci] = v4.y;
            tile[(nj + 2) * 65 + ci] = v4.z;
            tile[(nj + 3) * 65 + ci] = v4.w;
        }
        __syncthreads();
        const int r = t >> 2, c16 = (t & 3) * 16;
        union { u16 h[16]; uint4 q[2]; } pk;
        for (int j = 0; j < 16; j++) pk.h[j] = f2bf(tile[r * 65 + c16 + j]);
        u16* dst = xT + ((size_t)(b * NN + n0 + r)) * CC + c0 + c16;
        *(uint4*)dst = pk.q[0];
        *(uint4*)(dst + 8) = pk.q[1];
    } else {
        const int flat = (bid - 1024) * 1024 + t * 4;
        const int o = flat >> 8, c = flat & 255;
        const float* src = (o < 64)  ? (Wq + (size_t)o * CC + c)
                         : (o < 128) ? (Wk + (size_t)(o - 64) * CC + c)
                                     : (Wv + (size_t)(o - 128) * CC + c);
        const float4 v4 = *(const float4*)src;
        union { u16 h[4]; uint2 d; } pk;
        pk.h[0] = f2bf(v4.x); pk.h[1] = f2bf(v4.y);
        pk.h[2] = f2bf(v4.z); pk.h[3] = f2bf(v4.w);
        *(uint2*)(wbf + (size_t)o * CC + c) = pk.d;
    }
}

// ---------------------------------------------------------------------------
// qkv: 512 blocks (2/CU) x 512 thr. n-tile 32; wave: 48 W-rows x 32 n. (R5)
// ---------------------------------------------------------------------------
__global__ __launch_bounds__(512, 4) void qkv(
    const u16* __restrict__ xT, const u16* __restrict__ wbf,
    const float* __restrict__ bq, const float* __restrict__ bk,
    const float* __restrict__ bv,
    u16* __restrict__ qT, u16* __restrict__ kT, u16* __restrict__ v)
{
    __shared__ __align__(16) u16 sm[384 * 64 + 32 * 64];  // 53248 B
    u16* Ws = sm;             // [384][64] swizzled
    u16* Xs = sm + 384 * 64;  // [32][64] swizzled

    const int bid = blockIdx.x;
    const int b = bid >> 7, n0 = (bid & 127) * 32;
    const int t = threadIdx.x, lane = t & 63, w = t >> 6;
    const int col = lane & 15, quad = lane >> 4;

    f32x4 acc[3][2];
    for (int i = 0; i < 3; i++) { acc[i][0] = f32x4{0,0,0,0}; acc[i][1] = f32x4{0,0,0,0}; }

    for (int cc = 0; cc < 4; cc++) {
        const int c0 = cc * 64;
        for (int m = 0; m < 6; m++) {
            const int g = m * 512 + t;
            const int row = g >> 3, ch = g & 7;
            gll16(wbf + (size_t)row * CC + c0 + ((ch ^ (row & 7)) * 8), Ws + g * 8);
        }
        if (w < 4) {
            const int g = w * 64 + lane;
            const int n = g >> 3, ch = g & 7;
            gll16(xT + ((size_t)(b * NN + n0 + n)) * CC + c0 + ((ch ^ (n & 7)) * 8),
                  Xs + g * 8);
        }
        __syncthreads();
        for (int kk = 0; kk < 2; kk++) {
            s16x8 bx[2];
            for (int nt2 = 0; nt2 < 2; nt2++) {
                const int n = nt2 * 16 + col;
                bx[nt2] = *(const s16x8*)&Xs[n * 64 + (((kk * 4 + quad) ^ (n & 7)) * 8)];
            }
            for (int ot = 0; ot < 3; ot++) {
                const int row = w * 48 + ot * 16 + col;
                const s16x8 a = *(const s16x8*)&Ws[row * 64 + (((kk * 4 + quad) ^ (row & 7)) * 8)];
                acc[ot][0] = MFMA16(a, bx[0], acc[ot][0]);
                acc[ot][1] = MFMA16(a, bx[1], acc[ot][1]);
            }
        }
        __syncthreads();
    }
    for (int ot = 0; ot < 3; ot++) {
        const int og = w * 48 + ot * 16 + quad * 4;   // wave-uniform region
        for (int nt2 = 0; nt2 < 2; nt2++) {
            const int n = n0 + nt2 * 16 + col;
            if (og < 64) {
                union { u16 h[4]; uint2 d; } pk;
                for (int r = 0; r < 4; r++) pk.h[r] = f2bf(acc[ot][nt2][r] + bq[og + r]);
                *(uint2*)(qT + ((size_t)(b * NN + n)) * CQ + og) = pk.d;
            } else if (og < 128) {
                union { u16 h[4]; uint2 d; } pk;
                for (int r = 0; r < 4; r++) pk.h[r] = f2bf(acc[ot][nt2][r] + bk[og - 64 + r]);
                *(uint2*)(kT + ((size_t)(b * NN + n)) * CQ + (og - 64)) = pk.d;
            } else {
                for (int r = 0; r < 4; r++)
                    v[((size_t)(b * CC + og - 128 + r)) * NN + n] =
                        f2bf(acc[ot][nt2][r] + bv[og - 128 + r]);
            }
        }
    }
}

// ---------------------------------------------------------------------------
// flash_attn v5: R5 structure (j-split x2, 2 blocks/CU, skewed 1-barrier pipe)
// + V content swizzle (R6-verified: chunk^( (row>>1)&3 ) -> even per-quad-phase
//   bank distribution for PV b128 reads) + truncating P convert
// + combine folded in: jh=0 publishes Op0(bf16 partial)+l0 then RELEASE-flag;
//   jh=1 polls RELAXED (+1 acquire), then epilogue computes final
//   out = x + g*(O0+O1)/(l0+l1).  Pairwise flag only — no grid barrier (R6).
// ---------------------------------------------------------------------------
__global__ __launch_bounds__(512, 4) void flash_attn(
    const u16* __restrict__ qT, const u16* __restrict__ kT,
    const u16* __restrict__ v, const float* __restrict__ x,
    const float* __restrict__ gamma,
    u16* __restrict__ Op0, float* __restrict__ lws,
    int* __restrict__ flag, float* __restrict__ out)
{
    // u16 offsets: K0@0 K1@2048 | V0@4096 V1@12288 | P0@20480 P1@23040 (stride 40)
    __shared__ __align__(16) u16 sm[25600];   // 51200 B
    __shared__ float ls[128];
    __shared__ float linv[64];

    const int bid = blockIdx.x;
    const int p = bid & 7;                 // XCD pin
    const int b = p >> 1, jh = p & 1;
    const int qt = bid >> 3;
    const int n0 = qt * 64;
    const int jb = jh * 2048;
    const int t = threadIdx.x;
    const int lane = t & 63, wv = t >> 6;
    const int col = lane & 15, quad = lane >> 4;
    const int strip = wv & 3, jhi = wv >> 2;   // S-phase identity
    const int ih = wv >> 2, cq = wv & 3;       // PV-phase identity
    const int key2 = (col >> 1) & 3;           // V de-swizzle key

    s16x8 aq[2];
    {
        const u16* qp = qT + ((size_t)(b * NN + n0 + strip * 16 + col)) * CQ + quad * 8;
        aq[0] = *(const s16x8*)qp;
        aq[1] = *(const s16x8*)(qp + 32);
    }

    f32x4 o_[2][4];
    for (int i = 0; i < 2; i++) for (int j = 0; j < 4; j++) o_[i][j] = f32x4{0,0,0,0};
    float lac[4] = {0.f, 0.f, 0.f, 0.f};

    const int kg = wv * 64 + lane;             // valid for wv<4
    const int krow = kg >> 3;
    const u16* ksrc = kT + ((size_t)(b * NN + jb + krow)) * CQ + (((kg & 7) ^ (krow & 7)) * 8);
    const int kdo = kg * 8;
    const u16* vsrc[2];
    int vdo[2];
    for (int m = 0; m < 2; m++) {
        const int g = m * 512 + t;
        const int row = g >> 2;
        const int chc = (g & 3) ^ ((row >> 1) & 3);   // content chunk for this slot
        vdo[m] = g * 8;
        vsrc[m] = v + ((size_t)(b * CC + row)) * NN + jb + chc * 8;
    }

    auto issueK = [&](int jt, int kb) {
        if (wv < 4) gll16(ksrc + (size_t)jt * 32 * CQ, sm + kb * 2048 + kdo);
    };
    auto issueV = [&](int jt, int vb) {
        u16* base = sm + 4096 + vb * 8192;
        for (int m = 0; m < 2; m++)
            gll16(vsrc[m] + jt * 32, base + vdo[m]);
    };
    auto S_phase = [&](int kb, int pb) {
        const u16* Kb = sm + kb * 2048;
        u16* Pb = sm + 20480 + pb * 2560;
        f32x4 s = f32x4{0,0,0,0};
        for (int kk = 0; kk < 2; kk++) {
            const int jrow = jhi * 16 + col;
            const s16x8 bk_ = *(const s16x8*)
                &Kb[jrow * 64 + (((kk * 4 + quad) ^ (jrow & 7)) * 8)];
            s = MFMA16(aq[kk], bk_, s);
        }
        for (int r = 0; r < 4; r++) {
            const float pv = __expf(fminf(s[r], 60.f));
            lac[r] += pv;
            Pb[(strip * 16 + quad * 4 + r) * 40 + jhi * 16 + col] = f2bf_t(pv);
        }
    };
    auto PV_phase = [&](int pb, int vb) {
        const u16* Pb = sm + 20480 + pb * 2560;
        const u16* Vb = sm + 4096 + vb * 8192;
        s16x8 pa[2];
        for (int it2 = 0; it2 < 2; it2++)
            pa[it2] = *(const s16x8*)&Pb[((ih * 2 + it2) * 16 + col) * 40 + quad * 8];
        for (int ct = 0; ct < 4; ct++) {
            const int c = cq * 64 + ct * 16 + col;
            const s16x8 bv_ = *(const s16x8*)&Vb[c * 32 + ((quad ^ key2) * 8)];
            o_[0][ct] = MFMA16(pa[0], bv_, o_[0][ct]);
            o_[1][ct] = MFMA16(pa[1], bv_, o_[1][ct]);
        }
    };

    issueK(0, 0);
    issueV(0, 0);
    issueK(1, 1);
    __syncthreads();
    S_phase(0, 0);

    int vcur = 0, pcur = 0;
    for (int m = 0; m < 64; m++) {
        __syncthreads();      // drains prior-iter DMAs; P[pcur] visible
        issueV((m + 1 < 64) ? m + 1 : 63, vcur ^ 1);
        issueK((m + 2 < 64) ? m + 2 : 63, m & 1);
        PV_phase(pcur, vcur);
        if (m < 63) S_phase((m + 1) & 1, pcur ^ 1);
        vcur ^= 1; pcur ^= 1;
    }

    // ---- l reduce -> ls[jhi][..]
    for (int r = 0; r < 4; r++) {
        float lv = lac[r];
        lv += __shfl_xor(lv, 1, 64);
        lv += __shfl_xor(lv, 2, 64);
        lv += __shfl_xor(lv, 4, 64);
        lv += __shfl_xor(lv, 8, 64);
        lac[r] = lv;
    }
    if (col == 0)
        for (int r = 0; r < 4; r++)
            ls[jhi * 64 + strip * 16 + quad * 4 + r] = lac[r];
    __syncthreads();   // drains trailing DMAs before sm reuse; ls visible

    const int fid = qt * 4 + b;
    if (jh == 0) {
        // ---- publish l0 and bf16 partial O, then release flag
        if (t < 64)
            lws[(size_t)b * NN + n0 + t] = ls[t] + ls[64 + t];
        u16* Tu = sm;          // [128][136] u16 transpose buffer
        for (int rd = 0; rd < 2; rd++) {
            if ((cq >> 1) == rd) {
                const int cl = (cq & 1) * 64;
                for (int it2 = 0; it2 < 2; it2++) {
                    const int ib = (ih * 2 + it2) * 16 + quad * 4;
                    for (int ct = 0; ct < 4; ct++) {
                        const int c = cl + ct * 16 + col;
                        union { u16 h[4]; uint2 d; } pk;
                        for (int r = 0; r < 4; r++) pk.h[r] = f2bf(o_[it2][ct][r]);
                        *(uint2*)&Tu[c * 136 + ib] = pk.d;
                    }
                }
            }
            __syncthreads();
            const int cl = t >> 2, i0 = (t & 3) * 16;
            const int c = rd * 128 + cl;
            u16* dst = Op0 + ((size_t)(b * CC + c)) * NN + n0 + i0;
            *(uint4*)dst       = *(const uint4*)&Tu[cl * 136 + i0];
            *(uint4*)(dst + 8) = *(const uint4*)&Tu[cl * 136 + i0 + 8];
            __syncthreads();
        }
        // all waves' global stores drained by the barrier above; release publishes L2
        if (t == 0)
            __hip_atomic_store(&flag[fid], 1, __ATOMIC_RELEASE, __HIP_MEMORY_SCOPE_AGENT);
    } else {
        // ---- wait for partner (relaxed poll, single acquire), then combine
        if (t == 0) {
            while (__hip_atomic_load(&flag[fid], __ATOMIC_RELAXED,
                                     __HIP_MEMORY_SCOPE_AGENT) == 0)
                __builtin_amdgcn_s_sleep(1);
            (void)__hip_atomic_load(&flag[fid], __ATOMIC_ACQUIRE,
                                    __HIP_MEMORY_SCOPE_AGENT);
        }
        __syncthreads();
        if (t < 64)
            linv[t] = gamma[0] / (lws[(size_t)b * NN + n0 + t] + ls[t] + ls[64 + t]);
        __syncthreads();
        float* Tf = (float*)sm;    // [128][68] f32 transpose buffer
        for (int rd = 0; rd < 2; rd++) {
            if ((cq >> 1) == rd) {
                const int cl = (cq & 1) * 64;
                for (int it2 = 0; it2 < 2; it2++) {
                    const int ib = (ih * 2 + it2) * 16 + quad * 4;
                    for (int ct = 0; ct < 4; ct++) {
                        const int c = cl + ct * 16 + col;
                        *(float2*)&Tf[c * 68 + ib]     = float2{o_[it2][ct][0], o_[it2][ct][1]};
                        *(float2*)&Tf[c * 68 + ib + 2] = float2{o_[it2][ct][2], o_[it2][ct][3]};
                    }
                }
            }
            __syncthreads();
            const int cl = t >> 2, i0 = (t & 3) * 16;
            const int c = rd * 128 + cl;
            const u16* o0p = Op0 + ((size_t)(b * CC + c)) * NN + n0 + i0;
            const float* xp = x + ((size_t)(b * CC + c)) * NN + n0 + i0;
            float* op = out + ((size_t)(b * CC + c)) * NN + n0 + i0;
            for (int k = 0; k < 4; k++) {
                const float4 xv = *(const float4*)(xp + k * 4);
                const float4 o1 = *(const float4*)&Tf[cl * 68 + i0 + k * 4];
                const float4 li = *(const float4*)&linv[i0 + k * 4];
                float4 r;
                r.x = xv.x + (bf2f(o0p[k * 4 + 0]) + o1.x) * li.x;
                r.y = xv.y + (bf2f(o0p[k * 4 + 1]) + o1.y) * li.y;
                r.z = xv.z + (bf2f(o0p[k * 4 + 2]) + o1.z) * li.z;
                r.w = xv.w + (bf2f(o0p[k * 4 + 3]) + o1.w) * li.w;
                *(float4*)(op + k * 4) = r;
            }
            __syncthreads();
        }
    }
}

// ---------------------------------------------------------------------------
extern "C" void kernel_launch(void* const* d_in, const int* in_sizes, int n_in,
                              void* d_out, int out_size, void* d_ws, size_t ws_size,
                              hipStream_t stream)
{
    const float* x     = (const float*)d_in[0];
    const float* Wq    = (const float*)d_in[1];
    const float* bq    = (const float*)d_in[2];
    const float* Wk    = (const float*)d_in[3];
    const float* bk    = (const float*)d_in[4];
    const float* Wv    = (const float*)d_in[5];
    const float* bv    = (const float*)d_in[6];
    const float* gamma = (const float*)d_in[7];
    float* out = (float*)d_out;

    // ws (u16): xT 8.39MB (reused as Op0) | wbf 196KB (reused as lws) |
    //           qT 2.1MB | kT 2.1MB | v 8.39MB | flags 1KB
    u16* xT  = (u16*)d_ws;
    u16* wbf = xT  + (size_t)4 * NN * CC;
    u16* qTw = wbf + (size_t)384 * CC;
    u16* kTw = qTw + (size_t)4 * NN * CQ;
    u16* vw  = kTw + (size_t)4 * NN * CQ;
    int* flags = (int*)(vw + (size_t)4 * CC * NN);
    u16* Op0 = xT;                 // xT dead after qkv
    float* lws = (float*)wbf;      // wbf dead after qkv

    hipMemsetAsync(flags, 0, 256 * sizeof(int), stream);
    prep<<<1120, 256, 0, stream>>>(x, Wq, Wk, Wv, xT, wbf);
    qkv<<<512, 512, 0, stream>>>(xT, wbf, bq, bk, bv, qTw, kTw, vw);
    flash_attn<<<512, 512, 0, stream>>>(qTw, kTw, vw, x, gamma, Op0, lws, flags, out);
}

// Round 8
// 179.310 us; speedup vs baseline: 2.0725x; 1.0247x over previous
//
#include <hip/hip_runtime.h>
#include <hip/hip_bf16.h>

typedef unsigned short u16;
typedef unsigned int u32;
typedef float f32x4 __attribute__((ext_vector_type(4)));
typedef short s16x8 __attribute__((ext_vector_type(8)));

#define MFMA16(a, b, c) __builtin_amdgcn_mfma_f32_16x16x32_bf16(a, b, c, 0, 0, 0)

#define NN 4096
#define CC 256
#define CQ 64

__device__ __forceinline__ u16 f2bf(float x) {          // round-nearest-even
    union { float f; u32 u; } v; v.f = x;
    return (u16)((v.u + 0x7FFFu + ((v.u >> 16) & 1u)) >> 16);
}
__device__ __forceinline__ u16 f2bf_t(float x) {        // truncate (P only)
    union { float f; u32 u; } v; v.f = x;
    return (u16)(v.u >> 16);
}
__device__ __forceinline__ float bf2f(u16 u) {
    union { u32 u; float f; } v; v.u = ((u32)u) << 16;
    return v.f;
}
// async global->LDS, 16B/lane; dst = wave-uniform base + lane*16 (m104)
__device__ __forceinline__ void gll16(const void* g, void* l) {
    __builtin_amdgcn_global_load_lds(
        (const __attribute__((address_space(1))) void*)g,
        (__attribute__((address_space(3))) void*)l, 16, 0, 0);
}
// pack 8 f32 -> bf16x8 via v_cvt_pk_bf16_f32
__device__ __forceinline__ s16x8 pk8(float a0, float a1, float a2, float a3,
                                     float a4, float a5, float a6, float a7) {
    union { __hip_bfloat162 h[4]; s16x8 v8; } u;
    u.h[0] = __float22bfloat162_rn(float2{a0, a1});
    u.h[1] = __float22bfloat162_rn(float2{a2, a3});
    u.h[2] = __float22bfloat162_rn(float2{a4, a5});
    u.h[3] = __float22bfloat162_rn(float2{a6, a7});
    return u.v8;
}

// ---------------------------------------------------------------------------
// qkv v3 (self-contained — prep kernel eliminated):
// 512 blocks (2/CU) x 512 thr = 4b x 128 n-tiles(32). Reads x f32 directly
// (coalesced float4, register-prefetched next c-chunk), transposes through an
// 8.7KB f32 LDS tile Xf[64][34] (stride 34: frag-read bank (c*2+n)%32, 2-way
// = free). B-frags = 8 strided f32 reads + cvt_pk. A-frags (W) read straight
// from global f32 (L2-resident, 393KB/XCD) + cvt_pk — no W staging, no wbf.
// Outputs: qT/kT [b][n][64] bf16 (k-contig), v [b][c][n] bf16.
// ---------------------------------------------------------------------------
__global__ __launch_bounds__(512, 4) void qkv(
    const float* __restrict__ x, const float* __restrict__ Wq,
    const float* __restrict__ Wk, const float* __restrict__ Wv,
    const float* __restrict__ bq, const float* __restrict__ bk,
    const float* __restrict__ bv,
    u16* __restrict__ qT, u16* __restrict__ kT, u16* __restrict__ v)
{
    __shared__ __align__(16) float Xf[64 * 34];   // 8704 B

    const int bid = blockIdx.x;
    const int b = bid >> 7, n0 = (bid & 127) * 32;
    const int t = threadIdx.x, lane = t & 63, w = t >> 6;
    const int col = lane & 15, quad = lane >> 4;

    f32x4 acc[3][2];
    for (int i = 0; i < 3; i++) { acc[i][0] = f32x4{0,0,0,0}; acc[i][1] = f32x4{0,0,0,0}; }

    // x staging assignment: thread -> (c-row, 4-n segment)
    const int xc = t >> 3, xs = (t & 7) * 4;
    const float* xbase = x + ((size_t)(b * CC + xc)) * NN + n0 + xs;
    float4 xr = *(const float4*)xbase;

    // wave-uniform W base for each ot (rows w*48+ot*16 .. +16)
    const float* wb_[3];
    for (int ot = 0; ot < 3; ot++) {
        const int og = w * 48 + ot * 16;
        wb_[ot] = (og < 64)  ? Wq + (size_t)(og + col) * CC
                : (og < 128) ? Wk + (size_t)(og - 64 + col) * CC
                             : Wv + (size_t)(og - 128 + col) * CC;
    }

    for (int cc = 0; cc < 4; cc++) {
        const int c0 = cc * 64;
        __syncthreads();          // Xf free (prev compute done)
        *(float2*)&Xf[xc * 34 + xs]     = float2{xr.x, xr.y};
        *(float2*)&Xf[xc * 34 + xs + 2] = float2{xr.z, xr.w};
        if (cc < 3)
            xr = *(const float4*)(xbase + (size_t)(cc + 1) * 64 * NN);
        // hoisted W loads (12 dwordx4, independent -> one vmcnt batch)
        float4 wr[3][2][2];
        for (int ot = 0; ot < 3; ot++)
            for (int kk = 0; kk < 2; kk++) {
                const float* wp = wb_[ot] + c0 + kk * 32 + quad * 8;
                wr[ot][kk][0] = *(const float4*)wp;
                wr[ot][kk][1] = *(const float4*)(wp + 4);
            }
        __syncthreads();          // Xf ready
        for (int kk = 0; kk < 2; kk++) {
            s16x8 bx[2];
            for (int nt2 = 0; nt2 < 2; nt2++) {
                const float* xp = &Xf[(kk * 32 + quad * 8) * 34 + nt2 * 16 + col];
                bx[nt2] = pk8(xp[0], xp[34], xp[68], xp[102],
                              xp[136], xp[170], xp[204], xp[238]);
            }
            for (int ot = 0; ot < 3; ot++) {
                const float* f0 = (const float*)&wr[ot][kk][0];
                const s16x8 a = pk8(f0[0], f0[1], f0[2], f0[3],
                                    f0[4], f0[5], f0[6], f0[7]);
                acc[ot][0] = MFMA16(a, bx[0], acc[ot][0]);
                acc[ot][1] = MFMA16(a, bx[1], acc[ot][1]);
            }
        }
    }
    // epilogue (R5-verified): og regions wave-uniform 16-aligned
    for (int ot = 0; ot < 3; ot++) {
        const int og = w * 48 + ot * 16 + quad * 4;
        for (int nt2 = 0; nt2 < 2; nt2++) {
            const int n = n0 + nt2 * 16 + col;
            if (og < 64) {
                union { u16 h[4]; uint2 d; } pk;
                for (int r = 0; r < 4; r++) pk.h[r] = f2bf(acc[ot][nt2][r] + bq[og + r]);
                *(uint2*)(qT + ((size_t)(b * NN + n)) * CQ + og) = pk.d;
            } else if (og < 128) {
                union { u16 h[4]; uint2 d; } pk;
                for (int r = 0; r < 4; r++) pk.h[r] = f2bf(acc[ot][nt2][r] + bk[og - 64 + r]);
                *(uint2*)(kT + ((size_t)(b * NN + n)) * CQ + (og - 64)) = pk.d;
            } else {
                for (int r = 0; r < 4; r++)
                    v[((size_t)(b * CC + og - 128 + r)) * NN + n] =
                        f2bf(acc[ot][nt2][r] + bv[og - 128 + r]);
            }
        }
    }
}

// ---------------------------------------------------------------------------
// flash_attn v6 = R5 structure (j-split x2, 2 blocks/CU, skewed 1-barrier
// pipeline) + R6/R7-verified V content swizzle (chunk^((row>>1)&3): even
// per-quad bank spread for PV b128 reads) + truncating P convert.
// Combine fold REVERTED (R7: cross-XCD acquire nuked L2, +13us).
// LDS u16 offsets: K0@0 K1@2048 | V0@4096 V1@12288 | P0@20480 P1@23040 (st 40)
// ---------------------------------------------------------------------------
__global__ __launch_bounds__(512, 4) void flash_attn(
    const u16* __restrict__ qT, const u16* __restrict__ kT,
    const u16* __restrict__ v,
    u16* __restrict__ Op0, float* __restrict__ Op1,
    float* __restrict__ lws)
{
    __shared__ __align__(16) u16 sm[25600];   // 51200 B
    __shared__ float ls[128];

    const int bid = blockIdx.x;
    const int p = bid & 7;                 // XCD pin: (b, jh) per XCD
    const int b = p >> 1, jh = p & 1;
    const int n0 = (bid >> 3) * 64;
    const int jb = jh * 2048;
    const int t = threadIdx.x;
    const int lane = t & 63, wv = t >> 6;
    const int col = lane & 15, quad = lane >> 4;
    const int strip = wv & 3, jhi = wv >> 2;   // S-phase identity
    const int ih = wv >> 2, cq = wv & 3;       // PV-phase identity
    const int key2 = (col >> 1) & 3;           // V de-swizzle key

    s16x8 aq[2];
    {
        const u16* qp = qT + ((size_t)(b * NN + n0 + strip * 16 + col)) * CQ + quad * 8;
        aq[0] = *(const s16x8*)qp;
        aq[1] = *(const s16x8*)(qp + 32);
    }

    f32x4 o_[2][4];
    for (int i = 0; i < 2; i++) for (int j = 0; j < 4; j++) o_[i][j] = f32x4{0,0,0,0};
    float lac[4] = {0.f, 0.f, 0.f, 0.f};

    const int kg = wv * 64 + lane;             // valid for wv<4
    const int krow = kg >> 3;
    const u16* ksrc = kT + ((size_t)(b * NN + jb + krow)) * CQ + (((kg & 7) ^ (krow & 7)) * 8);
    const int kdo = kg * 8;
    const u16* vsrc[2];
    int vdo[2];
    for (int m = 0; m < 2; m++) {
        const int g = m * 512 + t;
        const int row = g >> 2;
        const int chc = (g & 3) ^ ((row >> 1) & 3);   // content chunk (swizzle)
        vdo[m] = g * 8;
        vsrc[m] = v + ((size_t)(b * CC + row)) * NN + jb + chc * 8;
    }

    auto issueK = [&](int jt, int kb) {
        if (wv < 4) gll16(ksrc + (size_t)jt * 32 * CQ, sm + kb * 2048 + kdo);
    };
    auto issueV = [&](int jt, int vb) {
        u16* base = sm + 4096 + vb * 8192;
        for (int m = 0; m < 2; m++)
            gll16(vsrc[m] + jt * 32, base + vdo[m]);
    };
    auto S_phase = [&](int kb, int pb) {
        const u16* Kb = sm + kb * 2048;
        u16* Pb = sm + 20480 + pb * 2560;
        f32x4 s = f32x4{0,0,0,0};
        for (int kk = 0; kk < 2; kk++) {
            const int jrow = jhi * 16 + col;
            const s16x8 bk_ = *(const s16x8*)
                &Kb[jrow * 64 + (((kk * 4 + quad) ^ (jrow & 7)) * 8)];
            s = MFMA16(aq[kk], bk_, s);
        }
        for (int r = 0; r < 4; r++) {
            const float pv = __expf(fminf(s[r], 60.f));
            lac[r] += pv;
            Pb[(strip * 16 + quad * 4 + r) * 40 + jhi * 16 + col] = f2bf_t(pv);
        }
    };
    auto PV_phase = [&](int pb, int vb) {
        const u16* Pb = sm + 20480 + pb * 2560;
        const u16* Vb = sm + 4096 + vb * 8192;
        s16x8 pa[2];
        for (int it2 = 0; it2 < 2; it2++)
            pa[it2] = *(const s16x8*)&Pb[((ih * 2 + it2) * 16 + col) * 40 + quad * 8];
        for (int ct = 0; ct < 4; ct++) {
            const int c = cq * 64 + ct * 16 + col;
            const s16x8 bv_ = *(const s16x8*)&Vb[c * 32 + ((quad ^ key2) * 8)];
            o_[0][ct] = MFMA16(pa[0], bv_, o_[0][ct]);
            o_[1][ct] = MFMA16(pa[1], bv_, o_[1][ct]);
        }
    };

    issueK(0, 0);
    issueV(0, 0);
    issueK(1, 1);
    __syncthreads();
    S_phase(0, 0);

    int vcur = 0, pcur = 0;
    for (int m = 0; m < 64; m++) {
        __syncthreads();      // drains prior-iter DMAs; P[pcur] visible
        issueV((m + 1 < 64) ? m + 1 : 63, vcur ^ 1);
        issueK((m + 2 < 64) ? m + 2 : 63, m & 1);
        PV_phase(pcur, vcur);
        if (m < 63) S_phase((m + 1) & 1, pcur ^ 1);
        vcur ^= 1; pcur ^= 1;
    }

    // ---- l reduce, publish per (b,jh)
    for (int r = 0; r < 4; r++) {
        float lv = lac[r];
        lv += __shfl_xor(lv, 1, 64);
        lv += __shfl_xor(lv, 2, 64);
        lv += __shfl_xor(lv, 4, 64);
        lv += __shfl_xor(lv, 8, 64);
        lac[r] = lv;
    }
    if (col == 0)
        for (int r = 0; r < 4; r++)
            ls[jhi * 64 + strip * 16 + quad * 4 + r] = lac[r];
    __syncthreads();   // drains trailing DMAs before sm reuse; ls visible
    if (t < 64)
        lws[(size_t)jh * 4 * NN + (size_t)b * NN + n0 + t] = ls[t] + ls[64 + t];

    // ---- epilogue: transpose O through LDS in 2 rounds of 128 c (R5)
    float* Tf = (float*)sm;    // [128][68] f32
    u16*  Tu = sm;             // [128][136] u16
    for (int rd = 0; rd < 2; rd++) {
        if ((cq >> 1) == rd) {
            const int cl = (cq & 1) * 64;
            for (int it2 = 0; it2 < 2; it2++) {
                const int ib = (ih * 2 + it2) * 16 + quad * 4;
                for (int ct = 0; ct < 4; ct++) {
                    const int c = cl + ct * 16 + col;
                    if (jh == 0) {
                        union { u16 h[4]; uint2 d; } pk;
                        for (int r = 0; r < 4; r++) pk.h[r] = f2bf(o_[it2][ct][r]);
                        *(uint2*)&Tu[c * 136 + ib] = pk.d;
                    } else {
                        *(float2*)&Tf[c * 68 + ib]     = float2{o_[it2][ct][0], o_[it2][ct][1]};
                        *(float2*)&Tf[c * 68 + ib + 2] = float2{o_[it2][ct][2], o_[it2][ct][3]};
                    }
                }
            }
        }
        __syncthreads();
        const int cl = t >> 2, i0 = (t & 3) * 16;
        const int c = rd * 128 + cl;
        if (jh == 0) {
            u16* dst = Op0 + ((size_t)(b * CC + c)) * NN + n0 + i0;
            *(uint4*)dst       = *(const uint4*)&Tu[cl * 136 + i0];
            *(uint4*)(dst + 8) = *(const uint4*)&Tu[cl * 136 + i0 + 8];
        } else {
            float* dst = Op1 + ((size_t)(b * CC + c)) * NN + n0 + i0;
            for (int k = 0; k < 4; k++)
                *(float4*)(dst + k * 4) = *(const float4*)&Tf[cl * 68 + i0 + k * 4];
        }
        __syncthreads();
    }
}

// ---------------------------------------------------------------------------
// combine: out = x + gamma * (O0 + O1) / (l0 + l1)   (in-place over d_out=O1)
// ---------------------------------------------------------------------------
__global__ __launch_bounds__(256) void combine(
    const float* __restrict__ x, const u16* __restrict__ Op0,
    const float* __restrict__ lws, const float* __restrict__ gamma,
    float* __restrict__ out)
{
    const size_t idx = ((size_t)blockIdx.x * 256 + threadIdx.x) * 4;
    const int b = (int)(idx >> 20);
    const int n = (int)(idx & (NN - 1));
    const float g = gamma[0];
    const float4 xv = *(const float4*)(x + idx);
    const float4 o1 = *(const float4*)(out + idx);
    const u16* o0p = Op0 + idx;
    const float4 l0 = *(const float4*)(lws + (size_t)b * NN + n);
    const float4 l1 = *(const float4*)(lws + (size_t)4 * NN + (size_t)b * NN + n);
    float4 r;
    r.x = xv.x + g * (bf2f(o0p[0]) + o1.x) / (l0.x + l1.x);
    r.y = xv.y + g * (bf2f(o0p[1]) + o1.y) / (l0.y + l1.y);
    r.z = xv.z + g * (bf2f(o0p[2]) + o1.z) / (l0.z + l1.z);
    r.w = xv.w + g * (bf2f(o0p[3]) + o1.w) / (l0.w + l1.w);
    *(float4*)(out + idx) = r;
}

// ---------------------------------------------------------------------------
extern "C" void kernel_launch(void* const* d_in, const int* in_sizes, int n_in,
                              void* d_out, int out_size, void* d_ws, size_t ws_size,
                              hipStream_t stream)
{
    const float* x     = (const float*)d_in[0];
    const float* Wq    = (const float*)d_in[1];
    const float* bq    = (const float*)d_in[2];
    const float* Wk    = (const float*)d_in[3];
    const float* bk    = (const float*)d_in[4];
    const float* Wv    = (const float*)d_in[5];
    const float* bv    = (const float*)d_in[6];
    const float* gamma = (const float*)d_in[7];
    float* out = (float*)d_out;

    // ws (u16): Op0 8.39MB | lws 128KB | qT 2.1MB | kT 2.1MB | v 8.39MB
    u16* Op0 = (u16*)d_ws;
    float* lws = (float*)(Op0 + (size_t)4 * NN * CC);
    u16* qTw = (u16*)(lws + (size_t)8 * NN);
    u16* kTw = qTw + (size_t)4 * NN * CQ;
    u16* vw  = kTw + (size_t)4 * NN * CQ;

    qkv<<<512, 512, 0, stream>>>(x, Wq, Wk, Wv, bq, bk, bv, qTw, kTw, vw);
    flash_attn<<<512, 512, 0, stream>>>(qTw, kTw, vw, Op0, out, lws);
    combine<<<4096, 256, 0, stream>>>(x, Op0, lws, gamma, out);
}

// Round 9
// 178.229 us; speedup vs baseline: 2.0851x; 1.0061x over previous
//
#include <hip/hip_runtime.h>
#include <hip/hip_bf16.h>

typedef unsigned short u16;
typedef unsigned int u32;
typedef float f32x4 __attribute__((ext_vector_type(4)));
typedef short s16x8 __attribute__((ext_vector_type(8)));

#define MFMA16(a, b, c) __builtin_amdgcn_mfma_f32_16x16x32_bf16(a, b, c, 0, 0, 0)

#define NN 4096
#define CC 256
#define CQ 64

__device__ __forceinline__ u16 f2bf(float x) {          // round-nearest-even
    union { float f; u32 u; } v; v.f = x;
    return (u16)((v.u + 0x7FFFu + ((v.u >> 16) & 1u)) >> 16);
}
__device__ __forceinline__ float bf2f(u16 u) {
    union { u32 u; float f; } v; v.u = ((u32)u) << 16;
    return v.f;
}
// async global->LDS, 16B/lane; dst = wave-uniform base + lane*16 (m104)
__device__ __forceinline__ void gll16(const void* g, void* l) {
    __builtin_amdgcn_global_load_lds(
        (const __attribute__((address_space(1))) void*)g,
        (__attribute__((address_space(3))) void*)l, 16, 0, 0);
}
// lane <- lane^1 value, DPP quad_perm(1,0,3,2) — VALU pipe, no LDS traffic
__device__ __forceinline__ float dpp_xor1(float x) {
    union { float f; int i; } a, r;
    a.f = x;
    r.i = __builtin_amdgcn_mov_dpp(a.i, 0xB1, 0xF, 0xF, true);
    return r.f;
}

// ---------------------------------------------------------------------------
// prep (R5-verified): blocks 0..1023: x -> xT[b][n][c] bf16; 1024..1119: W -> wbf
// ---------------------------------------------------------------------------
__global__ __launch_bounds__(256) void prep(
    const float* __restrict__ x, const float* __restrict__ Wq,
    const float* __restrict__ Wk, const float* __restrict__ Wv,
    u16* __restrict__ xT, u16* __restrict__ wbf)
{
    const int bid = blockIdx.x, t = threadIdx.x;
    if (bid < 1024) {
        __shared__ float tile[64 * 65];
        const int b = bid >> 8, ctile = (bid >> 6) & 3, ntile = bid & 63;
        const int c0 = ctile * 64, n0 = ntile * 64;
        const int cw = t >> 4, nj = (t & 15) * 4;
        for (int it = 0; it < 4; it++) {
            const int ci = it * 16 + cw;
            const float4 v4 = *(const float4*)(x + ((size_t)(b * CC + c0 + ci)) * NN + n0 + nj);
            tile[(nj + 0) * 65 + ci] = v4.x;
            tile[(nj + 1) * 65 + ci] = v4.y;
            tile[(nj + 2) * 65 + ci] = v4.z;
            tile[(nj + 3) * 65 + ci] = v4.w;
        }
        __syncthreads();
        const int r = t >> 2, c16 = (t & 3) * 16;
        union { u16 h[16]; uint4 q[2]; } pk;
        for (int j = 0; j < 16; j++) pk.h[j] = f2bf(tile[r * 65 + c16 + j]);
        u16* dst = xT + ((size_t)(b * NN + n0 + r)) * CC + c0 + c16;
        *(uint4*)dst = pk.q[0];
        *(uint4*)(dst + 8) = pk.q[1];
    } else {
        const int flat = (bid - 1024) * 1024 + t * 4;
        const int o = flat >> 8, c = flat & 255;
        const float* src = (o < 64)  ? (Wq + (size_t)o * CC + c)
                         : (o < 128) ? (Wk + (size_t)(o - 64) * CC + c)
                                     : (Wv + (size_t)(o - 128) * CC + c);
        const float4 v4 = *(const float4*)src;
        union { u16 h[4]; uint2 d; } pk;
        pk.h[0] = f2bf(v4.x); pk.h[1] = f2bf(v4.y);
        pk.h[2] = f2bf(v4.z); pk.h[3] = f2bf(v4.w);
        *(uint2*)(wbf + (size_t)o * CC + c) = pk.d;
    }
}

// ---------------------------------------------------------------------------
// qkv (R5-verified): 512 blocks (2/CU) x 512 thr, async swizzled staging.
// ---------------------------------------------------------------------------
__global__ __launch_bounds__(512, 4) void qkv(
    const u16* __restrict__ xT, const u16* __restrict__ wbf,
    const float* __restrict__ bq, const float* __restrict__ bk,
    const float* __restrict__ bv,
    u16* __restrict__ qT, u16* __restrict__ kT, u16* __restrict__ v)
{
    __shared__ __align__(16) u16 sm[384 * 64 + 32 * 64];  // 53248 B
    u16* Ws = sm;
    u16* Xs = sm + 384 * 64;

    const int bid = blockIdx.x;
    const int b = bid >> 7, n0 = (bid & 127) * 32;
    const int t = threadIdx.x, lane = t & 63, w = t >> 6;
    const int col = lane & 15, quad = lane >> 4;

    f32x4 acc[3][2];
    for (int i = 0; i < 3; i++) { acc[i][0] = f32x4{0,0,0,0}; acc[i][1] = f32x4{0,0,0,0}; }

    for (int cc = 0; cc < 4; cc++) {
        const int c0 = cc * 64;
        for (int m = 0; m < 6; m++) {
            const int g = m * 512 + t;
            const int row = g >> 3, ch = g & 7;
            gll16(wbf + (size_t)row * CC + c0 + ((ch ^ (row & 7)) * 8), Ws + g * 8);
        }
        if (w < 4) {
            const int g = w * 64 + lane;
            const int n = g >> 3, ch = g & 7;
            gll16(xT + ((size_t)(b * NN + n0 + n)) * CC + c0 + ((ch ^ (n & 7)) * 8),
                  Xs + g * 8);
        }
        __syncthreads();
        for (int kk = 0; kk < 2; kk++) {
            s16x8 bx[2];
            for (int nt2 = 0; nt2 < 2; nt2++) {
                const int n = nt2 * 16 + col;
                bx[nt2] = *(const s16x8*)&Xs[n * 64 + (((kk * 4 + quad) ^ (n & 7)) * 8)];
            }
            for (int ot = 0; ot < 3; ot++) {
                const int row = w * 48 + ot * 16 + col;
                const s16x8 a = *(const s16x8*)&Ws[row * 64 + (((kk * 4 + quad) ^ (row & 7)) * 8)];
                acc[ot][0] = MFMA16(a, bx[0], acc[ot][0]);
                acc[ot][1] = MFMA16(a, bx[1], acc[ot][1]);
            }
        }
        __syncthreads();
    }
    for (int ot = 0; ot < 3; ot++) {
        const int og = w * 48 + ot * 16 + quad * 4;
        for (int nt2 = 0; nt2 < 2; nt2++) {
            const int n = n0 + nt2 * 16 + col;
            if (og < 64) {
                union { u16 h[4]; uint2 d; } pk;
                for (int r = 0; r < 4; r++) pk.h[r] = f2bf(acc[ot][nt2][r] + bq[og + r]);
                *(uint2*)(qT + ((size_t)(b * NN + n)) * CQ + og) = pk.d;
            } else if (og < 128) {
                union { u16 h[4]; uint2 d; } pk;
                for (int r = 0; r < 4; r++) pk.h[r] = f2bf(acc[ot][nt2][r] + bk[og - 64 + r]);
                *(uint2*)(kT + ((size_t)(b * NN + n)) * CQ + (og - 64)) = pk.d;
            } else {
                for (int r = 0; r < 4; r++)
                    v[((size_t)(b * CC + og - 128 + r)) * NN + n] =
                        f2bf(acc[ot][nt2][r] + bv[og - 128 + r]);
            }
        }
    }
}

// ---------------------------------------------------------------------------
// flash_attn v7: Q-tile 128 rows, j-split x4 (512 blocks = 4b x 32qt x 4jq,
// 2/CU). 32-wide j tiles, 32 iters, skewed 1-barrier pipeline (R5/R8-verified).
// V-frag reuse x4 (it2 0..3), K-frag reuse x2 (2 strips). P-writes paired via
// DPP + cvt_pk -> b32 (half the LDS write ops). V content swizzle + stride-40
// P (R8-verified). Partials: jq<3 -> bf16 Op[jq]; jq==3 -> f32 into d_out.
// LDS u16: K0@0 K1@2048 | V0@4096 V1@12288 | P0@20480 P1@25600 (128x40) = 60KB.
// ---------------------------------------------------------------------------
__global__ __launch_bounds__(512, 4) void flash_attn(
    const u16* __restrict__ qT, const u16* __restrict__ kT,
    const u16* __restrict__ v,
    u16* __restrict__ Op0, u16* __restrict__ Op1, u16* __restrict__ Op2,
    float* __restrict__ lws, float* __restrict__ out)
{
    __shared__ __align__(16) u16 sm[30720];   // 61440 B
    __shared__ float ls[256];

    const int bid = blockIdx.x;
    const int p = bid & 7;                 // XCD pin: (b, jq-pair) per XCD
    const int b = p >> 1;
    const int inner = bid >> 3;            // 0..63
    const int qt = inner >> 1;             // 0..31  (128-row Q tiles)
    const int jq = (p & 1) * 2 + (inner & 1);
    const int n0 = qt * 128;
    const int jb = jq * 1024;
    const int t = threadIdx.x;
    const int lane = t & 63, wv = t >> 6;
    const int col = lane & 15, quad = lane >> 4;
    const int strip0 = wv & 3, jhi = wv >> 2;  // S: strips strip0, strip0+4
    const int ih = wv >> 2, cq = wv & 3;       // PV: i-half 64, c-range 64
    const int key2 = (col >> 1) & 3;           // V de-swizzle key

    // Q A-frags for 2 strips
    s16x8 aq[2][2];
    for (int st = 0; st < 2; st++) {
        const int row = n0 + (strip0 + st * 4) * 16 + col;
        const u16* qp = qT + ((size_t)(b * NN + row)) * CQ + quad * 8;
        aq[st][0] = *(const s16x8*)qp;
        aq[st][1] = *(const s16x8*)(qp + 32);
    }

    f32x4 o_[4][4];   // [it2 (16i)][ct (16c)]
    for (int i = 0; i < 4; i++) for (int j = 0; j < 4; j++) o_[i][j] = f32x4{0,0,0,0};
    float lac[2][4] = {{0.f,0.f,0.f,0.f},{0.f,0.f,0.f,0.f}};

    // staging addresses (R8-verified patterns, jb shifted)
    const int kg = wv * 64 + lane;             // valid for wv<4 (256 chunks)
    const int krow = kg >> 3;
    const u16* ksrc = kT + ((size_t)(b * NN + jb + krow)) * CQ + (((kg & 7) ^ (krow & 7)) * 8);
    const int kdo = kg * 8;
    const u16* vsrc[2];
    int vdo[2];
    for (int m = 0; m < 2; m++) {
        const int g = m * 512 + t;             // 1024 chunks = 256 rows x 4
        const int row = g >> 2;
        const int chc = (g & 3) ^ ((row >> 1) & 3);   // content swizzle
        vdo[m] = g * 8;
        vsrc[m] = v + ((size_t)(b * CC + row)) * NN + jb + chc * 8;
    }

    auto issueK = [&](int jt, int kb) {
        if (wv < 4) gll16(ksrc + (size_t)jt * 32 * CQ, sm + kb * 2048 + kdo);
    };
    auto issueV = [&](int jt, int vb) {
        u16* base = sm + 4096 + vb * 8192;
        for (int m = 0; m < 2; m++)
            gll16(vsrc[m] + jt * 32, base + vdo[m]);
    };
    auto S_phase = [&](int kb, int pb) {
        const u16* Kb = sm + kb * 2048;
        u16* Pb = sm + 20480 + pb * 5120;
        f32x4 s[2] = { f32x4{0,0,0,0}, f32x4{0,0,0,0} };
        for (int kk = 0; kk < 2; kk++) {
            const int jrow = jhi * 16 + col;
            const s16x8 bk_ = *(const s16x8*)
                &Kb[jrow * 64 + (((kk * 4 + quad) ^ (jrow & 7)) * 8)];
            s[0] = MFMA16(aq[0][kk], bk_, s[0]);
            s[1] = MFMA16(aq[1][kk], bk_, s[1]);
        }
        for (int st = 0; st < 2; st++) {
            const int prow = (strip0 + st * 4) * 16 + quad * 4;
            for (int r = 0; r < 4; r++) {
                const float pv = __expf(fminf(s[st][r], 60.f));
                lac[st][r] += pv;
                const float nb = dpp_xor1(pv);       // value from lane^1
                if ((col & 1) == 0) {                // even col packs (col, col+1)
                    union { __hip_bfloat162 h; u32 u; } pk;
                    pk.h = __float22bfloat162_rn(float2{pv, nb});
                    *(u32*)&Pb[(prow + r) * 40 + jhi * 16 + col] = pk.u;
                }
            }
        }
    };
    auto PV_phase = [&](int pb, int vb) {
        const u16* Pb = sm + 20480 + pb * 5120;
        const u16* Vb = sm + 4096 + vb * 8192;
        s16x8 pa[4];
        for (int it2 = 0; it2 < 4; it2++)
            pa[it2] = *(const s16x8*)&Pb[(ih * 64 + it2 * 16 + col) * 40 + quad * 8];
        for (int ct = 0; ct < 4; ct++) {
            const int c = cq * 64 + ct * 16 + col;
            const s16x8 bv_ = *(const s16x8*)&Vb[c * 32 + ((quad ^ key2) * 8)];
            for (int it2 = 0; it2 < 4; it2++)
                o_[it2][ct] = MFMA16(pa[it2], bv_, o_[it2][ct]);
        }
    };

    // skewed 1-barrier pipeline, 32 iters
    issueK(0, 0);
    issueV(0, 0);
    issueK(1, 1);
    __syncthreads();
    S_phase(0, 0);

    int vcur = 0, pcur = 0;
    for (int m = 0; m < 32; m++) {
        __syncthreads();      // drains prior-iter DMAs; P[pcur] visible
        issueV((m + 1 < 32) ? m + 1 : 31, vcur ^ 1);
        issueK((m + 2 < 32) ? m + 2 : 31, m & 1);
        PV_phase(pcur, vcur);
        if (m < 31) S_phase((m + 1) & 1, pcur ^ 1);
        vcur ^= 1; pcur ^= 1;
    }

    // ---- l reduce (16 j-cols in-wave), publish per jhi, sum, store partial l
    for (int st = 0; st < 2; st++)
        for (int r = 0; r < 4; r++) {
            float lv = lac[st][r];
            lv += __shfl_xor(lv, 1, 64);
            lv += __shfl_xor(lv, 2, 64);
            lv += __shfl_xor(lv, 4, 64);
            lv += __shfl_xor(lv, 8, 64);
            lac[st][r] = lv;
        }
    if (col == 0)
        for (int st = 0; st < 2; st++)
            for (int r = 0; r < 4; r++)
                ls[jhi * 128 + (strip0 + st * 4) * 16 + quad * 4 + r] = lac[st][r];
    __syncthreads();   // drains trailing DMAs before sm reuse; ls visible
    if (t < 128)
        lws[(size_t)jq * 4 * NN + (size_t)b * NN + n0 + t] = ls[t] + ls[128 + t];

    // ---- epilogue: 4 rounds of 64 c, transpose through LDS
    u16* Opd = (jq == 0) ? Op0 : (jq == 1) ? Op1 : Op2;
    u16*  Tu = sm;             // [64][136] u16
    float* Tf = (float*)sm;    // [64][132] f32
    for (int rd = 0; rd < 4; rd++) {
        if (cq == rd) {
            for (int it2 = 0; it2 < 4; it2++) {
                const int ib = ih * 64 + it2 * 16 + quad * 4;
                for (int ct = 0; ct < 4; ct++) {
                    const int cl = ct * 16 + col;
                    if (jq < 3) {
                        union { u16 h[4]; uint2 d; } pk;
                        for (int r = 0; r < 4; r++) pk.h[r] = f2bf(o_[it2][ct][r]);
                        *(uint2*)&Tu[cl * 136 + ib] = pk.d;
                    } else {
                        *(float2*)&Tf[cl * 132 + ib]     = float2{o_[it2][ct][0], o_[it2][ct][1]};
                        *(float2*)&Tf[cl * 132 + ib + 2] = float2{o_[it2][ct][2], o_[it2][ct][3]};
                    }
                }
            }
        }
        __syncthreads();
        const int cl = t >> 3, i0 = (t & 7) * 16;
        const int c = rd * 64 + cl;
        if (jq < 3) {
            u16* dst = Opd + ((size_t)(b * CC + c)) * NN + n0 + i0;
            *(uint4*)dst       = *(const uint4*)&Tu[cl * 136 + i0];
            *(uint4*)(dst + 8) = *(const uint4*)&Tu[cl * 136 + i0 + 8];
        } else {
            float* dst = out + ((size_t)(b * CC + c)) * NN + n0 + i0;
            for (int k = 0; k < 4; k++)
                *(float4*)(dst + k * 4) = *(const float4*)&Tf[cl * 132 + i0 + k * 4];
        }
        __syncthreads();
    }
}

// ---------------------------------------------------------------------------
// combine: out = x + gamma * (O0+O1+O2+O3) / (l0+l1+l2+l3), O3 in d_out (f32)
// ---------------------------------------------------------------------------
__global__ __launch_bounds__(256) void combine(
    const float* __restrict__ x, const u16* __restrict__ Op0,
    const u16* __restrict__ Op1, const u16* __restrict__ Op2,
    const float* __restrict__ lws, const float* __restrict__ gamma,
    float* __restrict__ out)
{
    const size_t idx = ((size_t)blockIdx.x * 256 + threadIdx.x) * 4;
    const int b = (int)(idx >> 20);
    const int n = (int)(idx & (NN - 1));
    const float g = gamma[0];
    const float4 xv = *(const float4*)(x + idx);
    const float4 o3 = *(const float4*)(out + idx);
    const u16* p0 = Op0 + idx;
    const u16* p1 = Op1 + idx;
    const u16* p2 = Op2 + idx;
    float4 lsum;
    {
        const size_t lb = (size_t)b * NN + n;
        const float4 l0 = *(const float4*)(lws + lb);
        const float4 l1 = *(const float4*)(lws + (size_t)4 * NN + lb);
        const float4 l2 = *(const float4*)(lws + (size_t)8 * NN + lb);
        const float4 l3 = *(const float4*)(lws + (size_t)12 * NN + lb);
        lsum.x = l0.x + l1.x + l2.x + l3.x;
        lsum.y = l0.y + l1.y + l2.y + l3.y;
        lsum.z = l0.z + l1.z + l2.z + l3.z;
        lsum.w = l0.w + l1.w + l2.w + l3.w;
    }
    float4 r;
    r.x = xv.x + g * (bf2f(p0[0]) + bf2f(p1[0]) + bf2f(p2[0]) + o3.x) / lsum.x;
    r.y = xv.y + g * (bf2f(p0[1]) + bf2f(p1[1]) + bf2f(p2[1]) + o3.y) / lsum.y;
    r.z = xv.z + g * (bf2f(p0[2]) + bf2f(p1[2]) + bf2f(p2[2]) + o3.z) / lsum.z;
    r.w = xv.w + g * (bf2f(p0[3]) + bf2f(p1[3]) + bf2f(p2[3]) + o3.w) / lsum.w;
    *(float4*)(out + idx) = r;
}

// ---------------------------------------------------------------------------
extern "C" void kernel_launch(void* const* d_in, const int* in_sizes, int n_in,
                              void* d_out, int out_size, void* d_ws, size_t ws_size,
                              hipStream_t stream)
{
    const float* x     = (const float*)d_in[0];
    const float* Wq    = (const float*)d_in[1];
    const float* bq    = (const float*)d_in[2];
    const float* Wk    = (const float*)d_in[3];
    const float* bk    = (const float*)d_in[4];
    const float* Wv    = (const float*)d_in[5];
    const float* bv    = (const float*)d_in[6];
    const float* gamma = (const float*)d_in[7];
    float* out = (float*)d_out;

    // ws (u16): xT 8.39MB (reused as Op0 after qkv) | wbf 0.2MB | Op1 8.39 |
    //           Op2 8.39 | lws 0.26MB | qT 2.1 | kT 2.1 | v 8.39  ≈ 38.2 MB
    u16* xT  = (u16*)d_ws;
    u16* wbf = xT  + (size_t)4 * NN * CC;
    u16* Op1 = wbf + (size_t)384 * CC;
    u16* Op2 = Op1 + (size_t)4 * NN * CC;
    float* lws = (float*)(Op2 + (size_t)4 * NN * CC);
    u16* qTw = (u16*)(lws + (size_t)16 * NN);
    u16* kTw = qTw + (size_t)4 * NN * CQ;
    u16* vw  = kTw + (size_t)4 * NN * CQ;
    u16* Op0 = xT;                 // xT dead after qkv

    prep<<<1120, 256, 0, stream>>>(x, Wq, Wk, Wv, xT, wbf);
    qkv<<<512, 512, 0, stream>>>(xT, wbf, bq, bk, bv, qTw, kTw, vw);
    flash_attn<<<512, 512, 0, stream>>>(qTw, kTw, vw, Op0, Op1, Op2, lws, out);
    combine<<<4096, 256, 0, stream>>>(x, Op0, Op1, Op2, lws, gamma, out);
}